// Round 2
// baseline (194.847 us; speedup 1.0000x reference)
//
#include <hip/hip_runtime.h>
#include <hip/hip_bf16.h>

// SAGEConv: N=10000 nodes, E=640000 edges, in_feat=128, out_feat=256.
// Inputs (per reference): h fp32 [10000,128], src/dst int32 [640000],
//                         W fp32 [256,256], b fp32 [256]. Output fp32 [10000,256].
// Pipeline: count-by-dst -> exclusive scan -> scatter edge ids (CSR buckets)
//           -> fp32->bf16 convert of h (and Acat self-half)
//           -> pull-mode mean aggregation (1 wave/node, fp32 accum, bf16 out)
//           -> MFMA bf16 GEMM  out = [h | h_N] @ W + b   (fp32 accum + fp32 out)
#define NN 10000
#define NE 640000
#define MPAD 10048  // 157 * 64

typedef __attribute__((ext_vector_type(8))) short bf16x8;
typedef __attribute__((ext_vector_type(4))) float f32x4;

__device__ __forceinline__ unsigned packbf(float x, float y) {
  __hip_bfloat16 a = __float2bfloat16(x);
  __hip_bfloat16 c = __float2bfloat16(y);
  unsigned short ua = __builtin_bit_cast(unsigned short, a);
  unsigned short uc = __builtin_bit_cast(unsigned short, c);
  return (unsigned)ua | ((unsigned)uc << 16);
}

__global__ void k_zero(int* __restrict__ p, int n) {
  int i = blockIdx.x * blockDim.x + threadIdx.x;
  if (i < n) p[i] = 0;
}

__global__ void k_count(const int* __restrict__ dst, int* __restrict__ cnt) {
  int e = blockIdx.x * blockDim.x + threadIdx.x;
  if (e < NE) atomicAdd(&cnt[dst[e]], 1);
}

// Single-block scan of 10000 degree counts -> exclusive offsets + cursor copy.
__global__ void k_scan(const int* __restrict__ cnt, int* __restrict__ offs,
                       int* __restrict__ cursor) {
  __shared__ int lds[1024];
  int t = threadIdx.x;
  int base = t * 10;
  int local[10];
  int s = 0;
#pragma unroll
  for (int i = 0; i < 10; i++) {
    int idx = base + i;
    int v = (idx < NN) ? cnt[idx] : 0;
    local[i] = s;  // exclusive within thread
    s += v;
  }
  lds[t] = s;
  __syncthreads();
  for (int off = 1; off < 1024; off <<= 1) {
    int add = (t >= off) ? lds[t - off] : 0;
    __syncthreads();
    lds[t] += add;
    __syncthreads();
  }
  int excl = (t == 0) ? 0 : lds[t - 1];
#pragma unroll
  for (int i = 0; i < 10; i++) {
    int idx = base + i;
    if (idx < NN) {
      int v = excl + local[i];
      offs[idx] = v;
      cursor[idx] = v;
    }
  }
  if (t == 1023) offs[NN] = lds[1023];  // = NE
}

__global__ void k_scatter(const int* __restrict__ src, const int* __restrict__ dst,
                          int* __restrict__ cursor, int* __restrict__ esrc) {
  int e = blockIdx.x * blockDim.x + threadIdx.x;
  if (e < NE) {
    int p = atomicAdd(&cursor[dst[e]], 1);
    esrc[p] = src[e];
  }
}

// fp32 h -> bf16 copy hb (row = 64 dwords of bf16x2) + self-half of Acat.
// One thread per (node, lane-pair): j = node*64 + lane, reads float2.
__global__ void k_convert(const float* __restrict__ h, unsigned* __restrict__ hb32,
                          unsigned* __restrict__ A32) {
  int j = blockIdx.x * blockDim.x + threadIdx.x;
  if (j >= NN * 64) return;
  int node = j >> 6;
  int lane = j & 63;
  float2 v = ((const float2*)h)[j];
  unsigned p = packbf(v.x, v.y);
  hb32[j] = p;
  A32[(size_t)node * 128 + lane] = p;  // self features 0..127
}

// One wave per node: lane l accumulates features {2l, 2l+1} (one dword of bf16x2)
// over the node's incoming-edge bucket (reads the bf16 copy hb).
__global__ void k_aggregate(const unsigned* __restrict__ hb32,
                            const int* __restrict__ offs,
                            const int* __restrict__ esrc,
                            unsigned* __restrict__ A32) {
  int wid = (blockIdx.x * blockDim.x + threadIdx.x) >> 6;
  int lane = threadIdx.x & 63;
  if (wid >= NN) return;
  int beg = offs[wid], end = offs[wid + 1];
  float a0 = 0.f, a1 = 0.f;
  int e = beg;
  for (; e + 3 < end; e += 4) {  // 4-wide for memory-level parallelism
    int s0 = esrc[e], s1 = esrc[e + 1], s2 = esrc[e + 2], s3 = esrc[e + 3];
    unsigned u0 = hb32[s0 * 64 + lane];
    unsigned u1 = hb32[s1 * 64 + lane];
    unsigned u2 = hb32[s2 * 64 + lane];
    unsigned u3 = hb32[s3 * 64 + lane];
    a0 += __uint_as_float(u0 << 16) + __uint_as_float(u1 << 16) +
          __uint_as_float(u2 << 16) + __uint_as_float(u3 << 16);
    a1 += __uint_as_float(u0 & 0xffff0000u) + __uint_as_float(u1 & 0xffff0000u) +
          __uint_as_float(u2 & 0xffff0000u) + __uint_as_float(u3 & 0xffff0000u);
  }
  for (; e < end; e++) {
    unsigned u0 = hb32[esrc[e] * 64 + lane];
    a0 += __uint_as_float(u0 << 16);
    a1 += __uint_as_float(u0 & 0xffff0000u);
  }
  int deg = end - beg;
  float inv = (deg > 0) ? 1.f / (float)deg : 0.f;
  a0 *= inv;
  a1 *= inv;
  A32[(size_t)wid * 128 + 64 + lane] = packbf(a0, a1);  // mean features 128..255
}

// C[64 rows x 64 cols] per block; 4 waves, each owns a 16-col strip.
// A (bf16) staged in LDS (row stride 264 -> 2-way bank aliasing only, 16B aligned);
// B fragments: W fp32 -> bf16 converted in-register, 16 cols x 256 k per wave.
__global__ __launch_bounds__(256) void k_gemm(const __hip_bfloat16* __restrict__ Acat,
                                              const float* __restrict__ W,
                                              const float* __restrict__ b,
                                              float* __restrict__ out) {
  __shared__ __align__(16) unsigned short As[64][264];
  int t = threadIdx.x;
  int bm = blockIdx.x;  // 0..156, 64 rows each
  int bn = blockIdx.y;  // 0..3,   64 cols each
  const unsigned short* Ag = (const unsigned short*)Acat;
#pragma unroll
  for (int i = 0; i < 8; i++) {  // 64 rows x 512B, 16B per thread-chunk
    int q = t + i * 256;
    int row = q >> 5;
    int c = q & 31;
    uint4 v = *(const uint4*)(Ag + ((size_t)(bm * 64 + row) * 256 + c * 8));
    *(uint4*)(&As[row][c * 8]) = v;
  }
  int w = t >> 6;
  int l = t & 63;
  int lm = l & 15;
  int kb = l >> 4;
  int col = bn * 64 + w * 16 + lm;
  // B fragment: lane holds B[k = ks*32 + kb*8 + j][n = col], j=0..7 (fp32->bf16)
  bf16x8 bfr[8];
#pragma unroll
  for (int ks = 0; ks < 8; ks++) {
#pragma unroll
    for (int j = 0; j < 8; j++) {
      float wv = W[(ks * 32 + kb * 8 + j) * 256 + col];
      bfr[ks][j] = (short)__builtin_bit_cast(unsigned short, __float2bfloat16(wv));
    }
  }
  __syncthreads();
  f32x4 acc[4];
#pragma unroll
  for (int r = 0; r < 4; r++) acc[r] = (f32x4){0.f, 0.f, 0.f, 0.f};
#pragma unroll
  for (int ks = 0; ks < 8; ks++) {
#pragma unroll
    for (int r = 0; r < 4; r++) {
      uint4 araw = *(const uint4*)(&As[r * 16 + lm][ks * 32 + kb * 8]);
      bf16x8 af = __builtin_bit_cast(bf16x8, araw);
      acc[r] = __builtin_amdgcn_mfma_f32_16x16x32_bf16(af, bfr[ks], acc[r], 0, 0, 0);
    }
  }
  float biasf = b[col];
#pragma unroll
  for (int r = 0; r < 4; r++) {
    int mbase = bm * 64 + r * 16 + kb * 4;  // C/D: row = (lane>>4)*4 + reg, col = lane&15
#pragma unroll
    for (int reg = 0; reg < 4; reg++) {
      int m = mbase + reg;
      if (m < NN) out[(size_t)m * 256 + col] = acc[r][reg] + biasf;
    }
  }
}

extern "C" void kernel_launch(void* const* d_in, const int* in_sizes, int n_in,
                              void* d_out, int out_size, void* d_ws, size_t ws_size,
                              hipStream_t stream) {
  const float* h = (const float*)d_in[0];
  const int* src = (const int*)d_in[1];
  const int* dst = (const int*)d_in[2];
  const float* W = (const float*)d_in[3];
  const float* b = (const float*)d_in[4];
  float* out = (float*)d_out;

  char* ws = (char*)d_ws;
  // ws layout (total ~10.4 MB):
  int* cnt = (int*)(ws + 0);                       // 10016 ints
  int* offs = (int*)(ws + 40064);                  // 10016 ints (uses 10001)
  int* cursor = (int*)(ws + 80128);                // 10016 ints
  int* esrc = (int*)(ws + 120192);                 // 640000 ints -> ends 2680192
  unsigned* hb32 = (unsigned*)(ws + 2680192);      // 10000*64 dwords -> ends 5240192
  unsigned* A32 = (unsigned*)(ws + 5240192);       // MPAD*128 dwords (bf16 Acat)
  __hip_bfloat16* Acat = (__hip_bfloat16*)A32;

  k_zero<<<40, 256, 0, stream>>>(cnt, 10016);
  k_count<<<2500, 256, 0, stream>>>(dst, cnt);
  k_scan<<<1, 1024, 0, stream>>>(cnt, offs, cursor);
  k_scatter<<<2500, 256, 0, stream>>>(src, dst, cursor, esrc);
  k_convert<<<2500, 256, 0, stream>>>(h, hb32, A32);
  k_aggregate<<<2500, 256, 0, stream>>>(hb32, offs, esrc, A32);
  k_gemm<<<dim3(157, 4), 256, 0, stream>>>(Acat, W, b, out);
}

// Round 3
// 154.764 us; speedup vs baseline: 1.2590x; 1.2590x over previous
//
#include <hip/hip_runtime.h>
#include <hip/hip_bf16.h>

// SAGEConv: N=10000 nodes, E=640000 edges, in_feat=128, out_feat=256.
// Inputs: h fp32 [10000,128], src/dst int32 [640000], W fp32 [256,256], b fp32 [256].
// Output fp32 [10000,256].
//
// Pipeline (NO global atomics — they serialize at the cross-XCD coherence point):
//   k_hist     : per-block LDS histogram of dst over a static 5000-edge range
//   k_colscan  : column scan of the 128x10000 histogram -> per-block bases + totals
//   k_scan     : exclusive scan of totals -> CSR offsets
//   k_scatter2 : re-walk same ranges, LDS cursor = offs + block base, scatter src ids
//   k_aggregate: 1 wave/node pull-mode mean over fp32 h (fp32 accum, bf16 out)
//   k_gemm     : MFMA bf16 [h | h_N] @ W + b, fp32 accum, fp32 out
#define NN 10000
#define NE 640000
#define MPAD 10048   // 157 * 64
#define HB 128       // histogram blocks
#define EPB 5000     // edges per histogram block (NE / HB)

typedef __attribute__((ext_vector_type(8))) short bf16x8;
typedef __attribute__((ext_vector_type(4))) float f32x4;

__device__ __forceinline__ unsigned packbf(float x, float y) {
  __hip_bfloat16 a = __float2bfloat16(x);
  __hip_bfloat16 c = __float2bfloat16(y);
  unsigned short ua = __builtin_bit_cast(unsigned short, a);
  unsigned short uc = __builtin_bit_cast(unsigned short, c);
  return (unsigned)ua | ((unsigned)uc << 16);
}

// Phase 1: per-block private histogram (LDS atomics only).
__global__ __launch_bounds__(256) void k_hist(const int* __restrict__ dst,
                                              int* __restrict__ ghist) {
  __shared__ int lh[10016];
  int t = threadIdx.x;
  int blk = blockIdx.x;
  for (int i = t; i < 10016; i += 256) lh[i] = 0;
  __syncthreads();
  int beg = blk * EPB, end = beg + EPB;
  for (int e = beg + t; e < end; e += 256) atomicAdd(&lh[dst[e]], 1);
  __syncthreads();
  for (int i = t; i < NN; i += 256) ghist[blk * NN + i] = lh[i];
}

// Phase 2: for each node v, exclusive-scan hist[:,v] over blocks (in-place),
// emit total count per node. No atomics; one thread per column.
__global__ void k_colscan(int* __restrict__ ghist, int* __restrict__ cnt) {
  int v = blockIdx.x * blockDim.x + threadIdx.x;
  if (v >= NN) return;
  int s = 0;
#pragma unroll 4
  for (int b = 0; b < HB; b++) {
    int t = ghist[b * NN + v];
    ghist[b * NN + v] = s;
    s += t;
  }
  cnt[v] = s;
}

// Single-block exclusive scan of 10000 counts -> CSR offsets.
__global__ void k_scan(const int* __restrict__ cnt, int* __restrict__ offs) {
  __shared__ int lds[1024];
  int t = threadIdx.x;
  int base = t * 10;
  int local[10];
  int s = 0;
#pragma unroll
  for (int i = 0; i < 10; i++) {
    int idx = base + i;
    int v = (idx < NN) ? cnt[idx] : 0;
    local[i] = s;
    s += v;
  }
  lds[t] = s;
  __syncthreads();
  for (int off = 1; off < 1024; off <<= 1) {
    int add = (t >= off) ? lds[t - off] : 0;
    __syncthreads();
    lds[t] += add;
    __syncthreads();
  }
  int excl = (t == 0) ? 0 : lds[t - 1];
#pragma unroll
  for (int i = 0; i < 10; i++) {
    int idx = base + i;
    if (idx < NN) offs[idx] = excl + local[i];
  }
  if (t == 1023) offs[NN] = lds[1023];  // = NE
}

// Phase 3: same static edge ranges as k_hist; LDS cursor seeded with
// offs[v] + this block's exclusive base; scatter src ids (LDS atomics only).
__global__ __launch_bounds__(256) void k_scatter2(const int* __restrict__ src,
                                                  const int* __restrict__ dst,
                                                  const int* __restrict__ offs,
                                                  const int* __restrict__ ghist,
                                                  int* __restrict__ esrc) {
  __shared__ int lc[10016];
  int t = threadIdx.x;
  int blk = blockIdx.x;
  for (int i = t; i < NN; i += 256) lc[i] = offs[i] + ghist[blk * NN + i];
  __syncthreads();
  int beg = blk * EPB, end = beg + EPB;
  for (int e = beg + t; e < end; e += 256) {
    int d = dst[e];
    int s = src[e];
    int p = atomicAdd(&lc[d], 1);
    esrc[p] = s;
  }
}

// One wave per node: lane l accumulates features {2l, 2l+1} over the node's
// incoming-edge bucket, gathering fp32 h rows (512B/edge, coalesced, L2-resident).
__global__ void k_aggregate(const float* __restrict__ h,
                            const int* __restrict__ offs,
                            const int* __restrict__ esrc,
                            unsigned* __restrict__ A32) {
  int wid = (blockIdx.x * blockDim.x + threadIdx.x) >> 6;
  int lane = threadIdx.x & 63;
  if (wid >= NN) return;
  const float2* h2 = (const float2*)h;  // row = 64 float2
  int beg = offs[wid], end = offs[wid + 1];
  float a0 = 0.f, a1 = 0.f;
  int e = beg;
  for (; e + 3 < end; e += 4) {  // 4-wide for memory-level parallelism
    int s0 = esrc[e], s1 = esrc[e + 1], s2 = esrc[e + 2], s3 = esrc[e + 3];
    float2 v0 = h2[s0 * 64 + lane];
    float2 v1 = h2[s1 * 64 + lane];
    float2 v2 = h2[s2 * 64 + lane];
    float2 v3 = h2[s3 * 64 + lane];
    a0 += (v0.x + v1.x) + (v2.x + v3.x);
    a1 += (v0.y + v1.y) + (v2.y + v3.y);
  }
  for (; e < end; e++) {
    float2 v0 = h2[esrc[e] * 64 + lane];
    a0 += v0.x;
    a1 += v0.y;
  }
  int deg = end - beg;
  float inv = (deg > 0) ? 1.f / (float)deg : 0.f;
  // mean features 128..255 of the concat row, stored bf16
  A32[(size_t)wid * 128 + 64 + lane] = packbf(a0 * inv, a1 * inv);
}

// C[64 x 64] per block; 4 waves, each owns a 16-col strip. A staged in LDS
// (row stride 264 shorts -> 4-bank rotation/row, 2-way aliasing only):
// self half converted fp32->bf16 from h, mean half copied bf16 from A32.
// B fragments: W fp32 -> bf16 in-register, 16 cols x 256 k per wave.
__global__ __launch_bounds__(256) void k_gemm(const float* __restrict__ h,
                                              const unsigned* __restrict__ A32,
                                              const float* __restrict__ W,
                                              const float* __restrict__ b,
                                              float* __restrict__ out) {
  __shared__ __align__(16) unsigned short As[64][264];
  int t = threadIdx.x;
  int bm = blockIdx.x;  // 0..156, 64 rows each
  int bn = blockIdx.y;  // 0..3,   64 cols each
  // Self half: 64 rows x 128 fp32 -> bf16. 2048 float4 chunks, 8 per thread.
#pragma unroll
  for (int i = 0; i < 8; i++) {
    int q = t + i * 256;
    int row = q >> 5;
    int c4 = q & 31;
    int gr = bm * 64 + row;
    if (gr > NN - 1) gr = NN - 1;  // clamp: avoid OOB read of h (out-store guards m)
    float4 v = *(const float4*)(h + (size_t)gr * 128 + c4 * 4);
    uint2 p;
    p.x = packbf(v.x, v.y);
    p.y = packbf(v.z, v.w);
    *(uint2*)(&As[row][c4 * 4]) = p;
  }
  // Mean half: 64 rows x 64 dwords (bf16x2). 2048 uint2 chunks, 8 per thread.
#pragma unroll
  for (int i = 0; i < 8; i++) {
    int q = t + i * 256;
    int row = q >> 5;
    int c = q & 31;
    int gr = bm * 64 + row;
    if (gr > NN - 1) gr = NN - 1;
    uint2 v = *(const uint2*)(A32 + (size_t)gr * 128 + 64 + c * 2);
    *(uint2*)(&As[row][128 + c * 4]) = v;
  }
  int w = t >> 6;
  int l = t & 63;
  int lm = l & 15;
  int kb = l >> 4;
  int col = bn * 64 + w * 16 + lm;
  // B fragment: lane holds B[k = ks*32 + kb*8 + j][n = col], j=0..7 (fp32->bf16)
  bf16x8 bfr[8];
#pragma unroll
  for (int ks = 0; ks < 8; ks++) {
#pragma unroll
    for (int j = 0; j < 8; j++) {
      float wv = W[(ks * 32 + kb * 8 + j) * 256 + col];
      bfr[ks][j] = (short)__builtin_bit_cast(unsigned short, __float2bfloat16(wv));
    }
  }
  __syncthreads();
  f32x4 acc[4];
#pragma unroll
  for (int r = 0; r < 4; r++) acc[r] = (f32x4){0.f, 0.f, 0.f, 0.f};
#pragma unroll
  for (int ks = 0; ks < 8; ks++) {
#pragma unroll
    for (int r = 0; r < 4; r++) {
      uint4 araw = *(const uint4*)(&As[r * 16 + lm][ks * 32 + kb * 8]);
      bf16x8 af = __builtin_bit_cast(bf16x8, araw);
      acc[r] = __builtin_amdgcn_mfma_f32_16x16x32_bf16(af, bfr[ks], acc[r], 0, 0, 0);
    }
  }
  float biasf = b[col];
#pragma unroll
  for (int r = 0; r < 4; r++) {
    int mbase = bm * 64 + r * 16 + kb * 4;  // C/D: row = (lane>>4)*4 + reg, col = lane&15
#pragma unroll
    for (int reg = 0; reg < 4; reg++) {
      int m = mbase + reg;
      if (m < NN) out[(size_t)m * 256 + col] = acc[r][reg] + biasf;
    }
  }
}

extern "C" void kernel_launch(void* const* d_in, const int* in_sizes, int n_in,
                              void* d_out, int out_size, void* d_ws, size_t ws_size,
                              hipStream_t stream) {
  const float* h = (const float*)d_in[0];
  const int* src = (const int*)d_in[1];
  const int* dst = (const int*)d_in[2];
  const float* W = (const float*)d_in[3];
  const float* b = (const float*)d_in[4];
  float* out = (float*)d_out;

  char* ws = (char*)d_ws;
  // ws layout (~12.9 MB):
  int* offs = (int*)(ws + 0);                  // 10016 ints (uses 10001)
  int* cnt = (int*)(ws + 40064);               // 10016 ints
  int* esrc = (int*)(ws + 80128);              // 640000 ints        -> ends 2640128
  int* ghist = (int*)(ws + 2640128);           // 128*10000 ints     -> ends 7760128
  unsigned* A32 = (unsigned*)(ws + 7760128);   // MPAD*128 dwords (bf16 concat rows)

  k_hist<<<HB, 256, 0, stream>>>(dst, ghist);
  k_colscan<<<40, 256, 0, stream>>>(ghist, cnt);
  k_scan<<<1, 1024, 0, stream>>>(cnt, offs);
  k_scatter2<<<HB, 256, 0, stream>>>(src, dst, offs, ghist, esrc);
  k_aggregate<<<2500, 256, 0, stream>>>(h, offs, esrc, A32);
  k_gemm<<<dim3(157, 4), 256, 0, stream>>>(h, A32, W, b, out);
}